// Round 11
// baseline (34.081 us; speedup 1.0000x reference)
//
#include <hip/hip_runtime.h>
#include <math.h>

#define NB   64
#define D    256
#define HW   25
#define TRI  32896         // 256*257/2
#define TS   64            // tile size (i and j)
#define PSTR 68            // padded p-row stride of transposed tile LDS (floats)
#define RSTR 260           // padded p-row stride of full-batch LDS (floats)

// tile id t (0..9) -> band pair (bi<=bj) of 4 bands
__device__ __forceinline__ void tile_bands(int t, int& bi, int& bj) {
    bi = (t < 4) ? 0 : (t < 7) ? 1 : (t < 9) ? 2 : 3;
    const int o4 = (bi == 0) ? 0 : (bi == 1) ? 4 : (bi == 2) ? 7 : 9;
    bj = bi + (t - o4);
}

// ---------------------------------------------------------------------------
// K1: full row sums, no e storage.  256 blocks = (64 b x 4 bands), 1024 thr.
// Stage all of f[b] transposed (fs[p][0..255], 26 KB).  Threads = 64(tx) x
// 16(ty): thread owns rows wbase+ty*4..+3 x cols tx*4..+3 (4x4 register tile
// covering the full 64 x 256 band in one shot).  Per p: av = broadcast
// ds_read_b128 (wave-uniform), bv = 64 consecutive float4 (bank-perfect).
// Row sums reduced over tx via LDS; 64 floats -> rs (collision-free).
// ---------------------------------------------------------------------------
__global__ __launch_bounds__(1024) void rowsum_kernel(const float* __restrict__ feat,
                                                      float* __restrict__ rs) {
    __shared__ __align__(16) float fs[HW * RSTR];   // 26 KB
    __shared__ float red[64][65];                   // 16.6 KB

    const int tid = threadIdx.x;
    const int b   = blockIdx.x >> 2;
    const int w   = blockIdx.x & 3;
    const int wbase = w * TS;
    const float* fb = feat + (size_t)b * D * HW;

    // stage all 256 rows transposed (coalesced global reads)
    for (int idx = tid; idx < D * HW; idx += 1024) {
        const int r = idx / HW;
        const int p = idx - r * HW;
        fs[p * RSTR + r] = fb[idx];
    }
    __syncthreads();

    const int tx = tid & 63;        // wave-varying: 64 consecutive j-chunks
    const int ty = tid >> 6;        // wave-uniform: i-chunk

    float acc[4][4] = {{0.f}};
#pragma unroll 5
    for (int p = 0; p < HW; ++p) {
        float4 av = *reinterpret_cast<const float4*>(&fs[p * RSTR + wbase + ty * 4]);
        float4 bv = *reinterpret_cast<const float4*>(&fs[p * RSTR + tx * 4]);
        float a4[4] = {av.x, av.y, av.z, av.w};
        float b4[4] = {bv.x, bv.y, bv.z, bv.w};
#pragma unroll
        for (int r = 0; r < 4; ++r)
#pragma unroll
            for (int q = 0; q < 4; ++q)
                acc[r][q] += fabsf(a4[r] + b4[q]) - fabsf(a4[r] - b4[q]);
    }

    float pi[4];
#pragma unroll
    for (int r = 0; r < 4; ++r) pi[r] = acc[r][0] + acc[r][1] + acc[r][2] + acc[r][3];
#pragma unroll
    for (int r = 0; r < 4; ++r) red[ty * 4 + r][tx] = pi[r];
    __syncthreads();

    if (tid < TS) {
        float s = 0.f;
#pragma unroll
        for (int x = 0; x < 64; x += 4) {
            float4 v = *reinterpret_cast<const float4*>(&red[tid][x]);
            s += (v.x + v.y) + (v.z + v.w);
        }
        rs[b * D + wbase + tid] = s;
    }
}

// ---------------------------------------------------------------------------
// K2: R6 tile geometry (640 blocks x 256 thr, 16x16, 4x4/thread).  Recompute
// e(i,j) from LDS-staged panels, then write the FINAL centered value once:
//   out = sc*(e - (rs_i + rs_j)/256),  sc = 0.5*exp(T)
// d_out is written once, never read; e never hits global memory.
// ---------------------------------------------------------------------------
__global__ __launch_bounds__(256) void center_kernel(const float* __restrict__ feat,
                                                     const float* __restrict__ temp,
                                                     const float* __restrict__ rs,
                                                     float* __restrict__ out) {
    __shared__ __align__(16) float as[HW * PSTR];
    __shared__ __align__(16) float bs[HW * PSTR];
    __shared__ float rsi[TS];
    __shared__ float rsj[TS];

    const int tid = threadIdx.x;
    const int blk = blockIdx.x;
    const int b   = blk / 10;
    const int t   = blk - b * 10;
    int bi, bj; tile_bands(t, bi, bj);
    const int ibase = bi * TS, jbase = bj * TS;
    const bool diag = (bi == bj);

    const float* fb = feat + (size_t)b * D * HW;

    // stage tile rows transposed (coalesced r-major global reads)
    for (int idx = tid; idx < TS * HW; idx += 256) {
        const int r = idx / HW;
        const int p = idx - r * HW;
        as[p * PSTR + r] = fb[(ibase + r) * HW + p];
    }
    if (!diag) {
        for (int idx = tid; idx < TS * HW; idx += 256) {
            const int r = idx / HW;
            const int p = idx - r * HW;
            bs[p * PSTR + r] = fb[(jbase + r) * HW + p];
        }
    }
    if (tid < TS)                rsi[tid]      = rs[b * D + ibase + tid];
    else if (tid < 2 * TS)       rsj[tid - TS] = rs[b * D + jbase + (tid - TS)];
    __syncthreads();

    const float* bsp = diag ? as : bs;
    const int tx = tid & 15;
    const int ty = tid >> 4;

    float acc[4][4] = {{0.f}};
#pragma unroll 5
    for (int p = 0; p < HW; ++p) {
        float4 av = *reinterpret_cast<const float4*>(&as[p * PSTR + ty * 4]);
        float4 bv = *reinterpret_cast<const float4*>(&bsp[p * PSTR + tx * 4]);
        float a4[4] = {av.x, av.y, av.z, av.w};
        float b4[4] = {bv.x, bv.y, bv.z, bv.w};
#pragma unroll
        for (int r = 0; r < 4; ++r)
#pragma unroll
            for (int q = 0; q < 4; ++q)
                acc[r][q] += fabsf(a4[r] + b4[q]) - fabsf(a4[r] - b4[q]);
    }

    const float sc = 0.5f * expf(temp[0]);
    float* ob = out + (size_t)b * TRI;
    if (diag) {
#pragma unroll
        for (int r = 0; r < 4; ++r) {
            const int i = ibase + ty * 4 + r;
            const int rowoff = (i * (513 - i)) >> 1;
            const float ri = rsi[ty * 4 + r];
#pragma unroll
            for (int q = 0; q < 4; ++q) {
                const int j = jbase + tx * 4 + q;
                if (j >= i)
                    ob[rowoff + (j - i)] =
                        sc * (acc[r][q] - (ri + rsj[tx * 4 + q]) * (1.0f / 256.0f));
            }
        }
    } else {
#pragma unroll
        for (int r = 0; r < 4; ++r) {
            const int i = ibase + ty * 4 + r;
            const int rowoff = (i * (513 - i)) >> 1;
            const float ri = rsi[ty * 4 + r];
#pragma unroll
            for (int q = 0; q < 4; ++q) {
                const int j = jbase + tx * 4 + q;
                ob[rowoff + (j - i)] =
                    sc * (acc[r][q] - (ri + rsj[tx * 4 + q]) * (1.0f / 256.0f));
            }
        }
    }
}

extern "C" void kernel_launch(void* const* d_in, const int* in_sizes, int n_in,
                              void* d_out, int out_size, void* d_ws, size_t ws_size,
                              hipStream_t stream) {
    const float* feat = (const float*)d_in[0];
    const float* temp = (const float*)d_in[1];
    float* out = (float*)d_out;
    float* rs  = (float*)d_ws;          // 64*256 floats = 64 KB row sums

    rowsum_kernel<<<NB * 4, 1024, 0, stream>>>(feat, rs);
    center_kernel<<<NB * 10, 256, 0, stream>>>(feat, temp, rs, out);
}